// Round 4
// baseline (67.907 us; speedup 1.0000x reference)
//
#include <hip/hip_runtime.h>
#include <hip/hip_bf16.h>

// TripletLoss: B=4096, D=1024.
// out[0] = loss scalar, out[1..] = distances (4096x4096 f32, row-major).
// ws: t_bf16 [B*D] ushort, g_bf16 [B*D] ushort, hn_key [B] int, pos [B] float.

typedef __bf16 bf16x8 __attribute__((ext_vector_type(8)));
typedef float  f32x4  __attribute__((ext_vector_type(4)));

__device__ __forceinline__ void gload16(const void* g, void* l) {
  __builtin_amdgcn_global_load_lds(
      (__attribute__((address_space(1))) void*)(g),
      (__attribute__((address_space(3))) void*)(l), 16, 0, 0);
}

__device__ __forceinline__ ushort f2bf(float x) {
  __hip_bfloat16 h = __float2bfloat16(x);
  return *reinterpret_cast<ushort*>(&h);
}

// order-preserving float->int key
__device__ __forceinline__ int fkey(float x) {
  int u = __float_as_int(x);
  return u >= 0 ? u : (u ^ 0x7fffffff);
}
__device__ __forceinline__ float funkey(int k) {
  return __int_as_float(k >= 0 ? k : (k ^ 0x7fffffff));
}

// ---------------------------------------------------------------- normalize
__global__ __launch_bounds__(256) void k_normalize(
    const float* __restrict__ t, const float* __restrict__ g,
    ushort* __restrict__ tb, ushort* __restrict__ gb,
    int* __restrict__ hn_key, int D) {
  const int row = blockIdx.x;
  const float* src = (blockIdx.y ? g : t) + (size_t)row * D;
  ushort*     dst  = (blockIdx.y ? gb : tb) + (size_t)row * D;

  float4 v = ((const float4*)src)[threadIdx.x];
  float ss = v.x * v.x + v.y * v.y + v.z * v.z + v.w * v.w;
#pragma unroll
  for (int off = 32; off; off >>= 1) ss += __shfl_down(ss, off);
  __shared__ float red[4];
  if ((threadIdx.x & 63) == 0) red[threadIdx.x >> 6] = ss;
  __syncthreads();
  float rn = red[0] + red[1] + red[2] + red[3];
  rn = 1.0f / fmaxf(sqrtf(rn), 1e-12f);

  ushort4 o;
  o.x = f2bf(v.x * rn); o.y = f2bf(v.y * rn);
  o.z = f2bf(v.z * rn); o.w = f2bf(v.w * rn);
  ((ushort4*)dst)[threadIdx.x] = o;

  if (blockIdx.y == 0 && threadIdx.x == 0) hn_key[row] = __float_as_int(1e9f);
}

// ---------------------------------------------------------------- GEMM fused
// 128x128 tile, BK=64, 512 thr = 8 waves (2M x 4N), per-wave 64x32.
// LDS 66KB -> 2 blocks/CU: co-resident block hides barrier/read stalls and
// overlaps epilogue store bursts with the other block's MFMA.
// One phase + ONE barrier per K-tile (double-buffered; prefetch issued before
// MFMA; boundary vmcnt(0) covered by the MFMA cluster + co-resident block).
// LDS swizzle: (r,k) at byte r*128 + (2k ^ ((r&7)<<4)); linear gload_lds dest
// + inverse-swizzled global source. Epilogue fuses distance store + per-row
// hard-negative min + diagonal pos.
__global__ __launch_bounds__(512, 4) void k_gemm_fused(
    const ushort* __restrict__ A, const ushort* __restrict__ Bm,
    const int* __restrict__ labels, float* __restrict__ Dout,
    int* __restrict__ hn_key, float* __restrict__ pos, int N, int K) {
  __shared__ __align__(16) ushort Atile[2][128 * 64];
  __shared__ __align__(16) ushort Btile[2][128 * 64];
  __shared__ int labR[128], labC[128], hnmin[128];

  const int tid  = threadIdx.x;
  const int lane = tid & 63;
  const int w    = tid >> 6;
  const int waveM = w >> 2, waveN = w & 3;   // 2M x 4N

  // XCD swizzle: 1024 blocks = 32x32 grid; each XCD owns a 16x8 block region
  // (concurrent working set A 4MB + B 2MB fits the 4MB per-XCD L2).
  const int nb  = N >> 7;                 // 32
  const int bid = blockIdx.x;
  int brow, bcol;
  if (nb == 32) {
    const int xcd = bid & 7;
    const int idx = bid >> 3;             // 0..127 -> 16 rows x 8 cols
    brow = ((xcd >> 2) << 4) + (idx >> 3);
    bcol = ((xcd & 3) << 3) + (idx & 7);
  } else {
    const int cpx = (nb * nb) >> 3;
    const int swz = (bid & 7) * cpx + (bid >> 3);
    brow = swz / nb; bcol = swz % nb;
  }
  const int rowBase = brow * 128;
  const int colBase = bcol * 128;

  // staging: round q covers rows q*64..q*64+63 (A: q=0,1; B: q=0,1)
  const int rr   = tid >> 3;                       // 0..63
  const int scol = ((tid & 7) ^ (rr & 7)) << 3;    // inverse-swizzled src col
  const ushort* aS = A  + (size_t)(rowBase + rr) * K + scol;
  const ushort* bS = Bm + (size_t)(colBase + rr) * K + scol;
  const int ldsDst = tid * 8;                      // ushort units within round

  // fragment read offsets (bytes within a buffer)
  const int sw  = (lane & 7) << 4;
  const int khi = ((lane >> 4) << 4);
  const int kx0 = khi ^ sw;
  const int kx1 = (64 + khi) ^ sw;
  const int aOffBase = (waveM * 64 + (lane & 15)) * 128;
  const int bOffBase = (waveN * 32 + (lane & 15)) * 128;

  // prologue: stage tile 0 into buf0; labels + hnmin init
  gload16(aS,                    &Atile[0][ldsDst]);
  gload16(aS + (size_t)64 * K,   &Atile[0][4096 + ldsDst]);
  gload16(bS,                    &Btile[0][ldsDst]);
  gload16(bS + (size_t)64 * K,   &Btile[0][4096 + ldsDst]);
  if (tid < 128)       labR[tid]        = labels[rowBase + tid];
  else if (tid < 256)  labC[tid - 128]  = labels[colBase + (tid - 128)];
  else if (tid < 384)  hnmin[tid - 256] = __float_as_int(1e9f);
  __syncthreads();   // drains vmcnt(0): tile 0 published

  f32x4 acc[4][2];
#pragma unroll
  for (int m = 0; m < 4; ++m)
#pragma unroll
    for (int n = 0; n < 2; ++n) acc[m][n] = (f32x4){0.f, 0.f, 0.f, 0.f};

  const int NT = K >> 6;   // 16
  for (int t = 0; t < NT; ++t) {
    const int cur = t & 1;
    const char* Ab = (const char*)&Atile[cur][0];
    const char* Bb = (const char*)&Btile[cur][0];
    const bool pre = (t + 1 < NT);

    // prefetch tile t+1 into the other buffer (freed by last tile's barrier)
    if (pre) {
      const size_t koff = (size_t)(t + 1) * 64;
      ushort* An = &Atile[cur ^ 1][0];
      ushort* Bn = &Btile[cur ^ 1][0];
      gload16(aS + koff,                  An + ldsDst);
      gload16(aS + (size_t)64 * K + koff, An + 4096 + ldsDst);
      gload16(bS + koff,                  Bn + ldsDst);
      gload16(bS + (size_t)64 * K + koff, Bn + 4096 + ldsDst);
    }

    bf16x8 af[4][2], bf[2][2];
#pragma unroll
    for (int mq = 0; mq < 4; ++mq) {
      const int ro = aOffBase + mq * 2048;
      af[mq][0] = *(const bf16x8*)(Ab + ro + kx0);
      af[mq][1] = *(const bf16x8*)(Ab + ro + kx1);
    }
#pragma unroll
    for (int nq = 0; nq < 2; ++nq) {
      const int ro = bOffBase + nq * 2048;
      bf[nq][0] = *(const bf16x8*)(Bb + ro + kx0);
      bf[nq][1] = *(const bf16x8*)(Bb + ro + kx1);
    }

    __builtin_amdgcn_s_setprio(1);
#pragma unroll
    for (int ks = 0; ks < 2; ++ks)
#pragma unroll
      for (int mq = 0; mq < 4; ++mq)
#pragma unroll
        for (int nq = 0; nq < 2; ++nq)
          acc[mq][nq] = __builtin_amdgcn_mfma_f32_16x16x32_bf16(
              af[mq][ks], bf[nq][ks], acc[mq][nq], 0, 0, 0);
    __builtin_amdgcn_s_setprio(0);

    if (pre) {
      asm volatile("s_waitcnt vmcnt(0)" ::: "memory");  // own t+1 loads landed
      __builtin_amdgcn_s_barrier();                     // all waves done+loaded
      asm volatile("" ::: "memory");
    }
  }

  // ---------------- fused epilogue: store distances + per-row hard-neg min
  const int ci = lane & 15;
  const int r4 = (lane >> 4) << 2;
  const bool diagBlk = (rowBase == colBase);
#pragma unroll
  for (int m = 0; m < 4; ++m) {
    const int gilB = waveM * 64 + m * 16 + r4;
#pragma unroll
    for (int r = 0; r < 4; ++r) {
      const int gil = gilB + r;
      const int li  = labR[gil];
      const size_t gi = (size_t)(rowBase + gil);
      float mn = 1e9f;
#pragma unroll
      for (int n = 0; n < 2; ++n) {
        const int gjl = waveN * 32 + n * 16 + ci;
        const float d = 1.0f - acc[m][n][r];
        Dout[gi * N + (colBase + gjl)] = d;
        if (labC[gjl] != li) mn = fminf(mn, d);
        if (diagBlk && gil == gjl) pos[gi] = d;
      }
#pragma unroll
      for (int off = 1; off < 16; off <<= 1) mn = fminf(mn, __shfl_xor(mn, off));
      if (ci == 0) atomicMin(&hnmin[gil], fkey(mn));
    }
  }
  __syncthreads();
  if (tid < 128) atomicMin(&hn_key[rowBase + tid], hnmin[tid]);
}

// ---------------------------------------------------------------- final sum
__global__ __launch_bounds__(256) void k_final(
    const int* __restrict__ hn_key, const float* __restrict__ pos,
    float* __restrict__ out, int N) {
  float s = 0.f;
  for (int i = threadIdx.x; i < N; i += 256) {
    const float hn = funkey(hn_key[i]);
    const float pr = pos[i] - hn + 1.0f;   // MARGIN = 1.0
    s += pr > 0.f ? pr : 0.f;              // hn==1e9 rows (no negatives) -> 0
  }
#pragma unroll
  for (int off = 32; off; off >>= 1) s += __shfl_down(s, off);
  __shared__ float red[4];
  if ((threadIdx.x & 63) == 0) red[threadIdx.x >> 6] = s;
  __syncthreads();
  if (threadIdx.x == 0) out[0] = (red[0] + red[1] + red[2] + red[3]) / (float)N;
}

extern "C" void kernel_launch(void* const* d_in, const int* in_sizes, int n_in,
                              void* d_out, int out_size, void* d_ws, size_t ws_size,
                              hipStream_t stream) {
  const float* t      = (const float*)d_in[0];
  const float* g      = (const float*)d_in[1];
  const int*   labels = (const int*)d_in[2];
  const int Bn = in_sizes[2];          // 4096
  const int D  = in_sizes[0] / Bn;     // 1024

  float* out  = (float*)d_out;
  float* dist = out + 1;

  ushort* tb     = (ushort*)d_ws;
  ushort* gb     = tb + (size_t)Bn * D;
  int*    hn_key = (int*)(gb + (size_t)Bn * D);
  float*  pos    = (float*)(hn_key + Bn);

  k_normalize<<<dim3(Bn, 2), 256, 0, stream>>>(t, g, tb, gb, hn_key, D);
  const int nb = Bn / 128;
  k_gemm_fused<<<dim3(nb * nb), 512, 0, stream>>>(tb, gb, labels, dist,
                                                  hn_key, pos, Bn, D);
  k_final<<<1, 256, 0, stream>>>(hn_key, pos, out, Bn);
}